// Round 19
// baseline (7464.672 us; speedup 1.0000x reference)
//
#include <hip/hip_runtime.h>
#include <cstdint>
#include <cstddef>

// Problem constants
constexpr int B_ = 16, T_ = 200, L_ = 250;
constexpr int IDIM = 512, ODIM = 80, DUNITS = 1024;
constexpr int ADIM = 128, ACH = 32, AK = 31;
constexpr int PRE = 256;
constexpr int TPAD = 208;

typedef _Float16 h16;
typedef _Float16 half8 __attribute__((ext_vector_type(8)));
typedef _Float16 half4 __attribute__((ext_vector_type(4)));
typedef float f32x4 __attribute__((ext_vector_type(4)));

// store-only flags per step (ints): z0w[256] @0 ; (gap) ; aw[16 reps][32] @288
constexpr int FSTEP = 800;
constexpr int FZ0W = 0, FAW = 288;

// ---- workspace byte offsets (16B-aligned) ----
constexpr size_t OFF_PE    = 0;          // pe_h   [16][128][208] f16
constexpr size_t OFF_H0H   = 851968;     // h0h    [2][16][1024] f16
constexpr size_t OFF_Z1H   = 917504;     // z1h    [2][16][1024] f16
constexpr size_t OFF_ATTC  = 983040;     // attc   [16][512] f16
constexpr size_t OFF_DP    = 999424;     // (unused)
constexpr size_t OFF_FLAGS = 1007616;    // flags  [250][800] int -> 1,807,616
constexpr size_t OFF_XT1   = 1807616;    // xT1 [16][264][128] f16 -> 2,888,960
constexpr size_t OFF_XTA   = 2888960;    // xTA [16][264][512] f16 -> 7,214,336
constexpr size_t OFF_XTB   = 7214336;    // xTB [16][264][512] f16 -> 11,539,712
constexpr size_t ZERO_BYTES= 11539712;   // zero span [0, here)
constexpr size_t OFF_MB    = 11539712;   // Mb     [8][64][8] f16
constexpr size_t OFF_WDR   = 11547904;   // Wdr    [128][1024] f16 (W_dec^T)
constexpr size_t OFF_PREN  = 11810048;   // pren_h [250][16][256] f16
constexpr size_t OFF_HSH   = 13858048;   // hs_h   [16][200][512] f16
constexpr size_t OFF_W0AH  = 17134848;   // W0ah   [4096][768]  f16
constexpr size_t OFF_WHH0  = 23426304;   // Whh0h  [4096][1024] f16
constexpr size_t OFF_WI1   = 31814912;   // Wz01h  [4096][1024] f16
constexpr size_t OFF_WHH1  = 40203520;   // Whh1h  [4096][1024] f16
constexpr size_t OFF_Z1ALL = 48592128;   // z1all  [250][16][1024] f16
constexpr size_t OFF_WTIN  = 56784128;   // wTin  [512][640]  f16
constexpr size_t OFF_WTMID = 57439488;   // wTmid [3][512][2560] f16
constexpr size_t OFF_WTOUT = 65303808;   // wTout [80][2560] f16 -> 65,713,408
constexpr size_t OFF_YSP   = 65713408;   // ysp [4000][96] f16 -> 66,481,408
constexpr size_t OFF_H1P   = 66481408;   // h1p [4000][256] f16 -> 68,529,408
constexpr size_t OFF_W1P   = 68529408;   // W1p [256][96] f16 -> 68,578,560
constexpr size_t OFF_W2P   = 68578560;   // W2p [256][256] f16 -> 68,709,632
constexpr size_t OFF_WENCP = 68709632;   // Wencp [128][512] f16 -> 68,840,704
constexpr size_t OFF_FWP   = 68840704;   // featWp [128][1024] f16 -> 69,102,848

__device__ __forceinline__ float fsig(float x) {
  x = fminf(fmaxf(x, -30.f), 30.f);
  return __builtin_amdgcn_rcpf(1.f + __expf(-x));
}
__device__ __forceinline__ float ftanh(float x) {
  x = fminf(fmaxf(x, -15.f), 15.f);
  const float e = __expf(2.f * x);
  return (e - 1.f) * __builtin_amdgcn_rcpf(e + 1.f);
}
__device__ __forceinline__ f32x4 mfma16(half8 a, half8 b, f32x4 c) {
  return __builtin_amdgcn_mfma_f32_16x16x32_f16(a, b, c, 0, 0, 0);
}
// agent-scope relaxed 16B load as 2x8B atomics (verified r8-r18 discipline)
__device__ __forceinline__ half8 load8_agent(const h16* p) {
  union { unsigned long long q[2]; half8 v; } cv;
  cv.q[0] = __hip_atomic_load((const unsigned long long*)p, __ATOMIC_RELAXED,
                              __HIP_MEMORY_SCOPE_AGENT);
  cv.q[1] = __hip_atomic_load(((const unsigned long long*)p) + 1, __ATOMIC_RELAXED,
                              __HIP_MEMORY_SCOPE_AGENT);
  return cv.v;
}
__device__ __forceinline__ int loadw(const int* p) {
  return __hip_atomic_load(p, __ATOMIC_RELAXED, __HIP_MEMORY_SCOPE_AGENT);
}
__device__ __forceinline__ void storew(int* p, int v) {
  __hip_atomic_store(p, v, __ATOMIC_RELAXED, __HIP_MEMORY_SCOPE_AGENT);
}
__device__ __forceinline__ void poll_n(const int* base, const int n) {
  if ((int)threadIdx.x < n) {
    const int* f = base + threadIdx.x;
    while (loadw(f) == 0) __builtin_amdgcn_s_sleep(1);
  }
  __syncthreads();
  __builtin_amdgcn_sched_barrier(0);
}
__device__ __forceinline__ void poll_all256(const int* base) {
  const int* f = base + threadIdx.x;
  while (loadw(f) == 0) __builtin_amdgcn_s_sleep(1);
  __syncthreads();
  __builtin_amdgcn_sched_barrier(0);
}

// ---------------- prep kernels ----------------

__global__ void k_zero(float4* __restrict__ p, int n4) {
  const int i = blockIdx.x * blockDim.x + threadIdx.x;
  if (i < n4) p[i] = make_float4(0.f, 0.f, 0.f, 0.f);
}

__global__ void k_precMb(const float* __restrict__ lconv, const float* __restrict__ W_att,
                         h16* __restrict__ Mb) {
  const int at = blockIdx.x, lane = threadIdx.x;
  const int a = at * 16 + (lane & 15);
  const int k0 = (lane >> 4) * 8;
  half8 o;
#pragma unroll
  for (int j = 0; j < 8; ++j) {
    const int k = k0 + j;
    float v = 0.f;
    if (k < AK)
      for (int c = 0; c < ACH; ++c) v += lconv[c * AK + k] * W_att[c * ADIM + a];
    o[j] = (h16)v;
  }
  *(half8*)(Mb + (size_t)(at * 64 + lane) * 8) = o;
}

__global__ void k_cvt_perm(const float* __restrict__ src, h16* __restrict__ dst,
                           const int K) {
  const int rr = blockIdx.x;
  const int u = rr >> 2, g = rr & 3;
  const float* s = src + (size_t)(g * 1024 + u) * K;
  h16* d = dst + (size_t)rr * K;
  for (int k = threadIdx.x; k < K; k += 256) d[k] = (h16)s[k];
}

// Wdr[a][k] = W_dec[k][a], f16
__global__ void k_cvt_wdec(const float* __restrict__ Wdec, h16* __restrict__ Wdr) {
  const int a = blockIdx.x;
  for (int k = threadIdx.x; k < 1024; k += 256)
    Wdr[(size_t)a * 1024 + k] = (h16)Wdec[(size_t)k * ADIM + a];
}

__global__ void k_cvt_f32f16(const float* __restrict__ src, h16* __restrict__ dst) {
  const size_t i = ((size_t)blockIdx.x * 256 + threadIdx.x) * 4;
  const float4 v = *(const float4*)(src + i);
  half4 o; o[0] = (h16)v.x; o[1] = (h16)v.y; o[2] = (h16)v.z; o[3] = (h16)v.w;
  *(half4*)(dst + i) = o;
}

// postnet weight repacks: wT[co][k*CIP + ci]
__global__ void k_cvt_wpin(const float* __restrict__ w, h16* __restrict__ o) {
  const int co = blockIdx.x;   // 512
  for (int i = threadIdx.x; i < 640; i += 256) {
    const int k = i >> 7, ci = i & 127;
    o[(size_t)co * 640 + i] = (ci < 80) ? (h16)w[((size_t)co * 80 + ci) * 5 + k] : (h16)0.f;
  }
}
__global__ void k_cvt_wpmid(const float* __restrict__ w, h16* __restrict__ o) {
  const int idx = blockIdx.x;  // 3*512
  const float* s = w + (size_t)idx * 512 * 5;
  h16* d = o + (size_t)idx * 2560;
  for (int i = threadIdx.x; i < 2560; i += 256) {
    const int k = i >> 9, ci = i & 511;
    d[i] = (h16)s[(size_t)ci * 5 + k];
  }
}
__global__ void k_cvt_wpout(const float* __restrict__ w, h16* __restrict__ o) {
  const int co = blockIdx.x;   // 80
  for (int i = threadIdx.x; i < 2560; i += 256) {
    const int k = i >> 9, ci = i & 511;
    o[(size_t)co * 2560 + i] = (h16)w[((size_t)co * 512 + ci) * 5 + k];
  }
}

// small GEMM prepacks
__global__ void k_p_ys(const float* __restrict__ ys, h16* __restrict__ ysp) {
  const int m = blockIdx.x;            // 4000: m = l*16+b
  const int l = m >> 4, b = m & 15;
  const int co = threadIdx.x;          // 96 threads
  h16 v = (h16)0.f;
  if (l > 0 && co < 80) v = (h16)ys[((size_t)b * L_ + (l - 1)) * ODIM + co];
  ysp[(size_t)m * 96 + co] = v;
}
__global__ void k_p_w1(const float* __restrict__ W1, h16* __restrict__ W1p) {
  const int p = blockIdx.x;            // 256
  const int o = threadIdx.x;           // 96
  W1p[(size_t)p * 96 + o] = (o < 80) ? (h16)W1[(size_t)o * PRE + p] : (h16)0.f;
}
__global__ void k_p_w2(const float* __restrict__ W2, h16* __restrict__ W2p) {
  const int p2 = blockIdx.x;           // 256
  const int p = threadIdx.x;           // 256
  W2p[(size_t)p2 * 256 + p] = (h16)W2[(size_t)p * PRE + p2];
}
__global__ void k_p_wenc(const float* __restrict__ We, h16* __restrict__ Wp) {
  const int a = blockIdx.x;            // 128
  for (int d = threadIdx.x; d < 512; d += 256)
    Wp[(size_t)a * 512 + d] = (h16)We[(size_t)d * ADIM + a];
}
__global__ void k_p_fw(const float* __restrict__ fw, const float* __restrict__ pw,
                       h16* __restrict__ Wp) {
  const int co = blockIdx.x;           // 128
  for (int d = threadIdx.x; d < 1024; d += 256) {
    h16 v = (h16)0.f;
    if (co < 80) v = (h16)fw[(size_t)d * ODIM + co];
    else if (co == 80) v = (h16)pw[d];
    Wp[(size_t)co * 1024 + d] = v;
  }
}

// ---------------- generic 16x64 MFMA GEMM (r17-verified) ----------------
template <int KCH, int EPI>
__global__ void __launch_bounds__(256) k_gemw(const h16* __restrict__ A,
    const h16* __restrict__ W, h16* __restrict__ dsth, float* __restrict__ dstf,
    float* __restrict__ dstf2, const float* __restrict__ bvec) {
  constexpr int KA = KCH * 32;
  const int m0 = blockIdx.x * 16, n0 = blockIdx.y * 64;
  const int lane = threadIdx.x & 63, wave = threadIdx.x >> 6;
  const int nloc = lane & 15, kl8 = (lane >> 4) * 8;
  const h16* wr = W + (size_t)(n0 + wave * 16 + nloc) * KA + kl8;
  half8 w[KCH];
#pragma unroll
  for (int c = 0; c < KCH; ++c) w[c] = *(const half8*)(wr + c * 32);
  const h16* ar = A + (size_t)(m0 + nloc) * KA + kl8;
  f32x4 acc = {0.f, 0.f, 0.f, 0.f};
#pragma unroll
  for (int c = 0; c < KCH; ++c)
    acc = mfma16(*(const half8*)(ar + c * 32), w[c], acc);
  const int n = n0 + wave * 16 + (lane & 15);
#pragma unroll
  for (int r = 0; r < 4; ++r) {
    const int m = m0 + 4 * (lane >> 4) + r;
    const float v = acc[r];
    if (EPI == 0) {
      dsth[(size_t)m * 256 + n] = (h16)fmaxf(v, 0.f);
    } else if (EPI == 1) {
      const int b = m / 200, t = m % 200;
      dsth[((size_t)b * 128 + n) * TPAD + t] = (h16)(v + bvec[n]);
    } else {
      const int b = m & 15, l = m >> 4;
      if (n < 80) {
        dstf[((size_t)b * L_ + l) * ODIM + n] = v;
        dsth[((size_t)b * 264 + l + 2) * 128 + n] = (h16)v;
      } else if (n == 80) {
        dstf2[(size_t)b * L_ + l] = v + bvec[0];
      }
    }
  }
}

// ---------------- MFMA postnet conv (r18-verified: weights once, loop b) ----------------
template <int CIP, int NK, bool TANH, bool FINAL>
__global__ void __launch_bounds__(256) k_cvmf(const h16* __restrict__ xT,
    const h16* __restrict__ wT, const float* __restrict__ gamma,
    const float* __restrict__ beta, h16* __restrict__ yT,
    const float* __restrict__ res, float* __restrict__ out0) {
  __shared__ float s_red[4][64][5];
  __shared__ float s_g[16][20];
  constexpr int KTOT = NK * 128;
  const int l0 = blockIdx.x * 16, co0 = blockIdx.y * 16;
  const int tid = threadIdx.x, lane = tid & 63, wave = tid >> 6;
  const int nloc = lane & 15, kl8 = (lane >> 4) * 8;
  const h16* wr = wT + (size_t)(co0 + nloc) * KTOT + wave * (NK * 32) + kl8;
  half8 w[NK];
#pragma unroll
  for (int c = 0; c < NK; ++c) w[c] = *(const half8*)(wr + c * 32);
  for (int b = 0; b < B_; ++b) {
    f32x4 acc = {0.f, 0.f, 0.f, 0.f};
    const h16* xb = xT + (size_t)b * 264 * CIP;
#pragma unroll
    for (int c = 0; c < NK; ++c) {
      const int kg = wave * (NK * 32) + c * 32;
      const int k = kg / CIP, ci = kg & (CIP - 1);
      const half8 a = *(const half8*)(xb + (size_t)(l0 + nloc + k) * CIP + ci + kl8);
      acc = mfma16(a, w[c], acc);
    }
#pragma unroll
    for (int r = 0; r < 4; ++r) s_red[wave][lane][r] = acc[r];
    __syncthreads();
    {
      const float v = s_red[0][lane][wave] + s_red[1][lane][wave]
                    + s_red[2][lane][wave] + s_red[3][lane][wave];
      s_g[lane & 15][4 * (lane >> 4) + wave] = v;
    }
    __syncthreads();
    {
      const int co_l = tid & 15, l_l = tid >> 4;
      const int co = co0 + co_l, l = l0 + l_l;
      if (l < L_ && tid < 256) {
        float v = gamma[co] * s_g[co_l][l_l] + beta[co];
        if (TANH) v = ftanh(v);
        if (FINAL) {
          const size_t o = ((size_t)b * L_ + l) * ODIM + co;
          out0[o] = res[o] + v;
        } else {
          yT[((size_t)b * 264 + l + 2) * 512 + co] = (h16)v;
        }
      }
    }
    __syncthreads();
  }
}

// ---------------- persistent scan (dp fused into att blocks via reg-held Wdr) ----------------

struct ScanP {
  const h16 *pe_h, *Mb, *Wdr, *hs_h, *pren_h;
  const h16 *W0ah, *Whh0h, *Wz01h, *Whh1h;
  h16 *h0h, *z1h, *attc;
  const float *gvw, *b0, *b1;
  const int *hlens;
  h16 *z1all;
  int *flags;
};

__device__ __forceinline__ void lstm0_partA(const h16* pren_t, const h16* z0p,
    const half8 wA[6], const half8 wH[8], f32x4& acc) {
  const int lane = threadIdx.x & 63, wave = threadIdx.x >> 6;
  const int nloc = lane & 15, kl8 = (lane >> 4) * 8;
  half8 rz[8];
#pragma unroll
  for (int c = 0; c < 8; ++c)
    rz[c] = load8_agent(z0p + nloc * DUNITS + wave * 256 + c * 32 + kl8);
#pragma unroll
  for (int c = 0; c < 8; ++c) acc = mfma16(rz[c], wH[c], acc);
#pragma unroll
  for (int c = 0; c < 6; ++c) {
    const int kg = wave * 192 + c * 32;
    if (kg >= 512)
      acc = mfma16(*(const half8*)(pren_t + nloc * PRE + (kg - 512) + kl8), wA[c], acc);
  }
}

__device__ __forceinline__ void lstm0_partB(const ScanP& P,
    h16* z0o, const int slab, const half8 wA[6], float& c0reg, f32x4 acc,
    float sred[4][64][5], float sg[16][20], h16* sho) {
  const int tid = threadIdx.x;
  const int lane = tid & 63, wave = tid >> 6;
  const int nloc = lane & 15, kl8 = (lane >> 4) * 8;
  half8 ra[6];
#pragma unroll
  for (int c = 0; c < 6; ++c) {
    const int kg = wave * 192 + c * 32;
    if (kg < 512) ra[c] = load8_agent(P.attc + nloc * IDIM + kg + kl8);
  }
#pragma unroll
  for (int c = 0; c < 6; ++c) {
    const int kg = wave * 192 + c * 32;
    if (kg < 512) acc = mfma16(ra[c], wA[c], acc);
  }
#pragma unroll
  for (int r = 0; r < 4; ++r) sred[wave][lane][r] = acc[r];
  __syncthreads();
  {
    const float v = sred[0][lane][wave] + sred[1][lane][wave]
                  + sred[2][lane][wave] + sred[3][lane][wave];
    sg[lane & 15][4 * (lane >> 4) + wave] = v;
  }
  __syncthreads();
  if (tid < 64) {
    const int ul = tid >> 4, b = tid & 15;
    const int u = slab * 4 + ul;
    const float xi = sg[ul * 4 + 0][b] + P.b0[u];
    const float xf = sg[ul * 4 + 1][b] + P.b0[1024 + u];
    const float xg = sg[ul * 4 + 2][b] + P.b0[2048 + u];
    const float xo = sg[ul * 4 + 3][b] + P.b0[3072 + u];
    const float cn = fsig(xf) * c0reg + fsig(xi) * ftanh(xg);
    c0reg = cn;
    sho[ul * 16 + b] = (h16)(fsig(xo) * ftanh(cn));
  }
  __syncthreads();
  if (tid < 16) {
    union { h16 h[4]; unsigned long long q; } u4;
#pragma unroll
    for (int j = 0; j < 4; ++j) u4.h[j] = sho[j * 16 + tid];
    __hip_atomic_store((unsigned long long*)(z0o + tid * DUNITS + slab * 4), u4.q,
                       __ATOMIC_RELAXED, __HIP_MEMORY_SCOPE_AGENT);
  }
}

__device__ __forceinline__ void lstm1_mm(const ScanP& P, const half8 r0[8],
    const half8 r1[8], h16* z1o, h16* z1all_s, const int slab,
    const half8 wI[8], const half8 wHH[8], float& c1reg,
    float sred[4][64][5], float sg[16][20], h16* sho) {
  const int tid = threadIdx.x;
  const int lane = tid & 63, wave = tid >> 6;
  f32x4 acc = {0.f, 0.f, 0.f, 0.f};
#pragma unroll
  for (int c = 0; c < 8; ++c) acc = mfma16(r0[c], wI[c], acc);
#pragma unroll
  for (int c = 0; c < 8; ++c) acc = mfma16(r1[c], wHH[c], acc);
#pragma unroll
  for (int r = 0; r < 4; ++r) sred[wave][lane][r] = acc[r];
  __syncthreads();
  {
    const float v = sred[0][lane][wave] + sred[1][lane][wave]
                  + sred[2][lane][wave] + sred[3][lane][wave];
    sg[lane & 15][4 * (lane >> 4) + wave] = v;
  }
  __syncthreads();
  if (tid < 64) {
    const int ul = tid >> 4, b = tid & 15;
    const int u = slab * 4 + ul;
    const float xi = sg[ul * 4 + 0][b] + P.b1[u];
    const float xf = sg[ul * 4 + 1][b] + P.b1[1024 + u];
    const float xg = sg[ul * 4 + 2][b] + P.b1[2048 + u];
    const float xo = sg[ul * 4 + 3][b] + P.b1[3072 + u];
    const float cn = fsig(xf) * c1reg + fsig(xi) * ftanh(xg);
    c1reg = cn;
    const float hn = fsig(xo) * ftanh(cn);
    const h16 hh = (h16)hn;
    z1all_s[b * DUNITS + u] = hh;
    sho[ul * 16 + b] = hh;
  }
  __syncthreads();
  if (tid < 16) {
    union { h16 h[4]; unsigned long long q; } u4;
#pragma unroll
    for (int j = 0; j < 4; ++j) u4.h[j] = sho[j * 16 + tid];
    __hip_atomic_store((unsigned long long*)(z1o + tid * DUNITS + slab * 4), u4.q,
                       __ATOMIC_RELAXED, __HIP_MEMORY_SCOPE_AGENT);
  }
}

__global__ void __launch_bounds__(256, 1) k_scan(const ScanP P) {
  __shared__ float s_red[4][64][5];
  __shared__ float s_g[16][20];
  __shared__ h16   s_ho[64];
  __shared__ float s_aw[240];
  __shared__ float s_dp[ADIM];
  __shared__ float s_gv[ADIM];
  __shared__ float s_ew[256];
  __shared__ float s_wt[208];
  __shared__ float s_par[4][512];
  __shared__ float s_r8[8];
  __shared__ float s_bc[2];
  __shared__ float s_cvpe[13][8][64][4];

  const int blk = blockIdx.x, tid = threadIdx.x;
  const int lane = tid & 63, wave = tid >> 6;
  constexpr int BD = B_ * DUNITS;

  if (blk < 16) {
    // ====== ATT block (batch b): in-register W_dec, dp computed in-block ======
    const int b = blk;
    const int hl = P.hlens[b];
    const int mtmax = (hl + 15) >> 4;
    const int slab = 240 + b;
    const int l15 = lane & 15;
    const int nloc = lane & 15, kl8 = (lane >> 4) * 8;
    half8 bfrag[8];
#pragma unroll
    for (int at = 0; at < 8; ++at)
      bfrag[at] = *(const half8*)(P.Mb + (size_t)(at * 64 + lane) * 8);
    half8 wA[6], wH[8];
    {
      const h16* wrA = P.W0ah + ((size_t)(slab * 16 + nloc)) * 768 + wave * 192 + kl8;
      const h16* wrH = P.Whh0h + ((size_t)(slab * 16 + nloc)) * 1024 + wave * 256 + kl8;
#pragma unroll
      for (int c = 0; c < 6; ++c) wA[c] = *(const half8*)(wrA + c * 32);
#pragma unroll
      for (int c = 0; c < 8; ++c) wH[c] = *(const half8*)(wrH + c * 32);
    }
    // W_dec slice: wave handles a-tiles [wave*32, +16) and [wave*32+16, +16), full K
    half8 wd0[32], wd1[32];
    {
      const h16* wr0 = P.Wdr + (size_t)(wave * 32 + nloc) * 1024 + kl8;
      const h16* wr1 = P.Wdr + (size_t)(wave * 32 + 16 + nloc) * 1024 + kl8;
#pragma unroll
      for (int c = 0; c < 32; ++c) wd0[c] = *(const half8*)(wr0 + c * 32);
#pragma unroll
      for (int c = 0; c < 32; ++c) wd1[c] = *(const half8*)(wr1 + c * 32);
    }
    if (tid < 240) {
      const int tt = tid - 15;
      s_aw[tid] = (tt >= 0 && tt < hl) ? (1.f / (float)hl) : 0.f;
    }
    if (tid < ADIM) s_gv[tid] = P.gvw[tid];
    __syncthreads();
    float c0reg = 0.f;

    for (int mi = 0; mi < 4; ++mi) {
      const int mt = wave + mi * 4;
      if (mt < mtmax) {
        half8 af;
#pragma unroll
        for (int j = 0; j < 8; ++j)
          af[j] = (h16)s_aw[mt * 16 + l15 + (lane >> 4) * 8 + j];
        const int t0 = mt * 16 + 4 * (lane >> 4);
        half4 pe[8];
#pragma unroll
        for (int at = 0; at < 8; ++at)
          pe[at] = *(const half4*)(P.pe_h + ((size_t)b * ADIM + at * 16 + l15) * TPAD + t0);
#pragma unroll
        for (int at = 0; at < 8; ++at) {
          f32x4 z4 = {0.f, 0.f, 0.f, 0.f};
          const f32x4 cv = mfma16(af, bfrag[at], z4);
          float4 o;
          o.x = cv[0] + (float)pe[at][0]; o.y = cv[1] + (float)pe[at][1];
          o.z = cv[2] + (float)pe[at][2]; o.w = cv[3] + (float)pe[at][3];
          *(float4*)&s_cvpe[mt][at][lane][0] = o;
        }
      }
    }
    __syncthreads();

    for (int i = 0; i < L_; ++i) {
      const h16* z0p = P.h0h + (size_t)(i & 1) * BD;
      h16* z0o = P.h0h + (size_t)((i & 1) ^ 1) * BD;
      int* sf = P.flags + (size_t)i * FSTEP;
      // ---- wait for z0(i-1); dp computed in-block from register weights ----
      if (i > 0) poll_all256(P.flags + (size_t)(i - 1) * FSTEP + FZ0W);
      {
        f32x4 da0 = {0.f, 0.f, 0.f, 0.f}, da1 = {0.f, 0.f, 0.f, 0.f};
#pragma unroll
        for (int c0 = 0; c0 < 32; c0 += 8) {
          half8 rz[8];
#pragma unroll
          for (int j = 0; j < 8; ++j)
            rz[j] = load8_agent(z0p + nloc * DUNITS + (c0 + j) * 32 + kl8);
#pragma unroll
          for (int j = 0; j < 8; ++j) {
            da0 = mfma16(rz[j], wd0[c0 + j], da0);
            da1 = mfma16(rz[j], wd1[c0 + j], da1);
          }
        }
        if ((lane >> 4) == (b >> 2)) {
          s_dp[wave * 32 + l15]      = da0[b & 3];
          s_dp[wave * 32 + 16 + l15] = da1[b & 3];
        }
      }
      __syncthreads();
      // ---- tanh-dot from precomputed cvpe (LDS) ----
#pragma unroll
      for (int mi = 0; mi < 4; ++mi) {
        const int mt = wave + mi * 4;
        if (mt < mtmax) {
          const int t0 = mt * 16 + 4 * (lane >> 4);
          float e0 = 0.f, e1 = 0.f, e2 = 0.f, e3 = 0.f;
#pragma unroll
          for (int at = 0; at < 8; ++at) {
            const float4 v = *(const float4*)&s_cvpe[mt][at][lane][0];
            const int a = at * 16 + l15;
            const float g = s_gv[a], d = s_dp[a];
            e0 += g * ftanh(v.x + d);
            e1 += g * ftanh(v.y + d);
            e2 += g * ftanh(v.z + d);
            e3 += g * ftanh(v.w + d);
          }
#pragma unroll
          for (int o = 1; o < 16; o <<= 1) {
            e0 += __shfl_xor(e0, o); e1 += __shfl_xor(e1, o);
            e2 += __shfl_xor(e2, o); e3 += __shfl_xor(e3, o);
          }
          if (l15 == 0) {
            s_ew[t0 + 0] = e0; s_ew[t0 + 1] = e1; s_ew[t0 + 2] = e2; s_ew[t0 + 3] = e3;
          }
        }
      }
      __syncthreads();
      // ---- softmax (scale 2.0) ----
      const float val = (tid < hl) ? 2.f * s_ew[tid] : -3.0e38f;
      float m = val;
#pragma unroll
      for (int o = 32; o > 0; o >>= 1) m = fmaxf(m, __shfl_xor(m, o));
      if ((tid & 63) == 0) s_r8[tid >> 6] = m;
      __syncthreads();
      if (tid == 0) s_bc[0] = fmaxf(fmaxf(s_r8[0], s_r8[1]), fmaxf(s_r8[2], s_r8[3]));
      __syncthreads();
      const float pp = (tid < hl) ? __expf(val - s_bc[0]) : 0.f;
      float ssum = pp;
#pragma unroll
      for (int o = 32; o > 0; o >>= 1) ssum += __shfl_xor(ssum, o);
      if ((tid & 63) == 0) s_r8[4 + (tid >> 6)] = ssum;
      __syncthreads();
      if (tid == 0) s_bc[1] = __builtin_amdgcn_rcpf(s_r8[4] + s_r8[5] + s_r8[6] + s_r8[7]);
      __syncthreads();
      if (tid < T_) {
        const float w = pp * s_bc[1];
        s_wt[tid] = w;
        s_aw[15 + tid] = w;
      }
      __syncthreads();
      const h16* hsb = P.hs_h + (size_t)b * T_ * IDIM;
      {
        const int d0 = lane * 8;
        const h16* hp = hsb + d0;
        float a8[8] = {0.f, 0.f, 0.f, 0.f, 0.f, 0.f, 0.f, 0.f};
        int tt = wave;
        for (; tt + 12 < hl; tt += 16) {
          const half8 h0 = *(const half8*)(hp + (size_t)tt * IDIM);
          const half8 h1 = *(const half8*)(hp + (size_t)(tt + 4) * IDIM);
          const half8 h2 = *(const half8*)(hp + (size_t)(tt + 8) * IDIM);
          const half8 h3 = *(const half8*)(hp + (size_t)(tt + 12) * IDIM);
          const float w0 = s_wt[tt], w1 = s_wt[tt + 4];
          const float w2 = s_wt[tt + 8], w3 = s_wt[tt + 12];
#pragma unroll
          for (int j = 0; j < 8; ++j)
            a8[j] += w0 * (float)h0[j] + w1 * (float)h1[j]
                   + w2 * (float)h2[j] + w3 * (float)h3[j];
        }
        for (; tt < hl; tt += 4) {
          const half8 hv = *(const half8*)(hp + (size_t)tt * IDIM);
          const float wt = s_wt[tt];
#pragma unroll
          for (int j = 0; j < 8; ++j) a8[j] += wt * (float)hv[j];
        }
#pragma unroll
        for (int j = 0; j < 8; ++j) s_par[wave][d0 + j] = a8[j];
      }
      __syncthreads();
      {
        const int d = tid * 2;
        const float cx0 = s_par[0][d] + s_par[1][d] + s_par[2][d] + s_par[3][d];
        const float cx1 = s_par[0][d + 1] + s_par[1][d + 1] + s_par[2][d + 1]
                        + s_par[3][d + 1];
        union { h16 h[2]; unsigned u; } cv;
        cv.h[0] = (h16)cx0; cv.h[1] = (h16)cx1;
        __hip_atomic_store((unsigned*)(P.attc + b * IDIM + d), cv.u,
                           __ATOMIC_RELAXED, __HIP_MEMORY_SCOPE_AGENT);
      }
      asm volatile("s_waitcnt vmcnt(0)" ::: "memory");
      __syncthreads();
      if (tid < 16) storew(sf + FAW + tid * 32 + b, 1);
      f32x4 acc0 = {0.f, 0.f, 0.f, 0.f};
      lstm0_partA(P.pren_h + (size_t)i * (B_ * PRE), z0p, wA, wH, acc0);
      poll_n(sf + FAW + (blk & 15) * 32, 16);
      lstm0_partB(P, z0o, slab, wA, c0reg, acc0, s_red, s_g, s_ho);
      asm volatile("s_waitcnt vmcnt(0)" ::: "memory");
      __syncthreads();
      if (tid == 0) storew(sf + FZ0W + blk, 1);
      for (int mi = 0; mi < 4; ++mi) {
        const int mt = wave + mi * 4;
        if (mt < mtmax) {
          half8 af;
#pragma unroll
          for (int j = 0; j < 8; ++j)
            af[j] = (h16)s_aw[mt * 16 + l15 + (lane >> 4) * 8 + j];
          const int t0 = mt * 16 + 4 * (lane >> 4);
          half4 pe[8];
#pragma unroll
          for (int at = 0; at < 8; ++at)
            pe[at] = *(const half4*)(P.pe_h + ((size_t)b * ADIM + at * 16 + l15) * TPAD + t0);
#pragma unroll
          for (int at = 0; at < 8; ++at) {
            f32x4 z4 = {0.f, 0.f, 0.f, 0.f};
            const f32x4 cv = mfma16(af, bfrag[at], z4);
            float4 o;
            o.x = cv[0] + (float)pe[at][0]; o.y = cv[1] + (float)pe[at][1];
            o.z = cv[2] + (float)pe[at][2]; o.w = cv[3] + (float)pe[at][3];
            *(float4*)&s_cvpe[mt][at][lane][0] = o;
          }
        }
      }
      __syncthreads();
    }
    return;
  }

  // ============ GEMM block ============
  const int g = blk - 16;
  const bool dbl = (g < 16);
  half8 wA0[6], wH0[8], wI1a[8], wHH1a[8], wI1b[8], wHH1b[8];
  {
    const int nloc = lane & 15, kl8 = (lane >> 4) * 8;
    const h16* wrA = P.W0ah + ((size_t)(g * 16 + nloc)) * 768 + wave * 192 + kl8;
    const h16* wrH = P.Whh0h + ((size_t)(g * 16 + nloc)) * 1024 + wave * 256 + kl8;
    const h16* wrI = P.Wz01h + ((size_t)(g * 16 + nloc)) * 1024 + wave * 256 + kl8;
    const h16* wrX = P.Whh1h + ((size_t)(g * 16 + nloc)) * 1024 + wave * 256 + kl8;
#pragma unroll
    for (int c = 0; c < 6; ++c) wA0[c] = *(const half8*)(wrA + c * 32);
#pragma unroll
    for (int c = 0; c < 8; ++c) wH0[c] = *(const half8*)(wrH + c * 32);
#pragma unroll
    for (int c = 0; c < 8; ++c) wI1a[c] = *(const half8*)(wrI + c * 32);
#pragma unroll
    for (int c = 0; c < 8; ++c) wHH1a[c] = *(const half8*)(wrX + c * 32);
    if (dbl) {
      const h16* wrI2 = P.Wz01h + ((size_t)((240 + g) * 16 + nloc)) * 1024 + wave * 256 + kl8;
      const h16* wrX2 = P.Whh1h + ((size_t)((240 + g) * 16 + nloc)) * 1024 + wave * 256 + kl8;
#pragma unroll
      for (int c = 0; c < 8; ++c) wI1b[c] = *(const half8*)(wrI2 + c * 32);
#pragma unroll
      for (int c = 0; c < 8; ++c) wHH1b[c] = *(const half8*)(wrX2 + c * 32);
    }
  }
  float c0reg = 0.f, c1a = 0.f, c1b = 0.f;
  const int nloc = lane & 15, kl8 = (lane >> 4) * 8;

  for (int i = 0; i < L_; ++i) {
    const h16* z0p = P.h0h + (size_t)(i & 1) * BD;
    h16* z0o = P.h0h + (size_t)((i & 1) ^ 1) * BD;
    const h16* z1p = P.z1h + (size_t)((i & 1) ^ 1) * BD;
    h16* z1o = P.z1h + (size_t)(i & 1) * BD;
    int* sf = P.flags + (size_t)i * FSTEP;
    if (i > 0) poll_all256(P.flags + (size_t)(i - 1) * FSTEP + FZ0W);
    if (i > 0) {
      half8 r0[8], r1[8];
#pragma unroll
      for (int c = 0; c < 8; ++c)
        r0[c] = load8_agent(z0p + nloc * DUNITS + wave * 256 + c * 32 + kl8);
#pragma unroll
      for (int c = 0; c < 8; ++c)
        r1[c] = load8_agent(z1p + nloc * DUNITS + wave * 256 + c * 32 + kl8);
      h16* z1s = P.z1all + (size_t)(i - 1) * BD;
      lstm1_mm(P, r0, r1, z1o, z1s, g, wI1a, wHH1a, c1a, s_red, s_g, s_ho);
      if (dbl)
        lstm1_mm(P, r0, r1, z1o, z1s, 240 + g, wI1b, wHH1b, c1b, s_red, s_g, s_ho);
    }
    f32x4 acc0 = {0.f, 0.f, 0.f, 0.f};
    lstm0_partA(P.pren_h + (size_t)i * (B_ * PRE), z0p, wA0, wH0, acc0);
    poll_n(sf + FAW + (blk & 15) * 32, 16);
    lstm0_partB(P, z0o, g, wA0, c0reg, acc0, s_red, s_g, s_ho);
    asm volatile("s_waitcnt vmcnt(0)" ::: "memory");
    __syncthreads();
    if (tid == 0) storew(sf + FZ0W + blk, 1);
  }
  poll_all256(P.flags + (size_t)(L_ - 1) * FSTEP + FZ0W);
  {
    const h16* z0p = P.h0h + (size_t)(L_ & 1) * BD;
    const h16* z1p = P.z1h + (size_t)((L_ & 1) ^ 1) * BD;
    h16* z1o = P.z1h + (size_t)(L_ & 1) * BD;
    h16* z1s = P.z1all + (size_t)(L_ - 1) * BD;
    half8 r0[8], r1[8];
#pragma unroll
    for (int c = 0; c < 8; ++c)
      r0[c] = load8_agent(z0p + nloc * DUNITS + wave * 256 + c * 32 + kl8);
#pragma unroll
    for (int c = 0; c < 8; ++c)
      r1[c] = load8_agent(z1p + nloc * DUNITS + wave * 256 + c * 32 + kl8);
    lstm1_mm(P, r0, r1, z1o, z1s, g, wI1a, wHH1a, c1a, s_red, s_g, s_ho);
    if (dbl)
      lstm1_mm(P, r0, r1, z1o, z1s, 240 + g, wI1b, wHH1b, c1b, s_red, s_g, s_ho);
  }
}

// ---------------- launch ----------------

extern "C" void kernel_launch(void* const* d_in, const int* in_sizes, int n_in,
                              void* d_out, int out_size, void* d_ws, size_t ws_size,
                              hipStream_t stream) {
  const float* hs    = (const float*)d_in[0];
  const int*   hlens = (const int*)d_in[1];
  const float* ys    = (const float*)d_in[2];
  const float* W_enc = (const float*)d_in[3];
  const float* b_enc = (const float*)d_in[4];
  const float* W_dec = (const float*)d_in[5];
  const float* W_att = (const float*)d_in[6];
  const float* lconv = (const float*)d_in[7];
  const float* gvw   = (const float*)d_in[8];
  const float* pW1   = (const float*)d_in[10];
  const float* pW2   = (const float*)d_in[11];
  const float* Wih0  = (const float*)d_in[12];
  const float* Whh0  = (const float*)d_in[13];
  const float* b0    = (const float*)d_in[14];
  const float* Wih1  = (const float*)d_in[15];
  const float* Whh1  = (const float*)d_in[16];
  const float* b1    = (const float*)d_in[17];
  const float* featW = (const float*)d_in[18];
  const float* probW = (const float*)d_in[19];
  const float* probB = (const float*)d_in[20];
  const float* pwin  = (const float*)d_in[21];
  const float* pgin  = (const float*)d_in[22];
  const float* pbin  = (const float*)d_in[23];
  const float* pwmid = (const float*)d_in[24];
  const float* pgmid = (const float*)d_in[25];
  const float* pbmid = (const float*)d_in[26];
  const float* pwout = (const float*)d_in[27];
  const float* pgout = (const float*)d_in[28];
  const float* pbout = (const float*)d_in[29];

  char* ws = (char*)d_ws;
  h16*   pe_h   = (h16*)(ws + OFF_PE);
  h16*   h0h    = (h16*)(ws + OFF_H0H);
  h16*   z1h    = (h16*)(ws + OFF_Z1H);
  h16*   attc_h = (h16*)(ws + OFF_ATTC);
  int*   flags  = (int*)(ws + OFF_FLAGS);
  h16*   xT1    = (h16*)(ws + OFF_XT1);
  h16*   xTA    = (h16*)(ws + OFF_XTA);
  h16*   xTB    = (h16*)(ws + OFF_XTB);
  h16*   Mb     = (h16*)(ws + OFF_MB);
  h16*   Wdr    = (h16*)(ws + OFF_WDR);
  h16*   pren_h = (h16*)(ws + OFF_PREN);
  h16*   hs_h   = (h16*)(ws + OFF_HSH);
  h16*   W0ah   = (h16*)(ws + OFF_W0AH);
  h16*   Whh0h  = (h16*)(ws + OFF_WHH0);
  h16*   Wz01h  = (h16*)(ws + OFF_WI1);
  h16*   Whh1h  = (h16*)(ws + OFF_WHH1);
  h16*   z1all  = (h16*)(ws + OFF_Z1ALL);
  h16*   wTin   = (h16*)(ws + OFF_WTIN);
  h16*   wTmid  = (h16*)(ws + OFF_WTMID);
  h16*   wTout  = (h16*)(ws + OFF_WTOUT);
  h16*   ysp    = (h16*)(ws + OFF_YSP);
  h16*   h1p    = (h16*)(ws + OFF_H1P);
  h16*   W1p    = (h16*)(ws + OFF_W1P);
  h16*   W2p    = (h16*)(ws + OFF_W2P);
  h16*   Wencp  = (h16*)(ws + OFF_WENCP);
  h16*   featWp = (h16*)(ws + OFF_FWP);

  float* out0 = (float*)d_out;
  float* out1 = out0 + (size_t)B_ * L_ * ODIM;
  float* out2 = out1 + (size_t)B_ * L_ * ODIM;

  // prep
  hipLaunchKernelGGL(k_zero, dim3((ZERO_BYTES / 16 + 255) / 256), dim3(256), 0, stream,
                     (float4*)ws, (int)(ZERO_BYTES / 16));
  hipLaunchKernelGGL(k_precMb, dim3(8), dim3(64), 0, stream, lconv, W_att, Mb);
  hipLaunchKernelGGL(k_cvt_perm, dim3(4096), dim3(256), 0, stream, Wih0, W0ah, 768);
  hipLaunchKernelGGL(k_cvt_perm, dim3(4096), dim3(256), 0, stream, Whh0, Whh0h, 1024);
  hipLaunchKernelGGL(k_cvt_perm, dim3(4096), dim3(256), 0, stream, Wih1, Wz01h, 1024);
  hipLaunchKernelGGL(k_cvt_perm, dim3(4096), dim3(256), 0, stream, Whh1, Whh1h, 1024);
  hipLaunchKernelGGL(k_cvt_wdec, dim3(128), dim3(256), 0, stream, W_dec, Wdr);
  hipLaunchKernelGGL(k_cvt_f32f16, dim3(1600), dim3(256), 0, stream, hs, hs_h);
  hipLaunchKernelGGL(k_cvt_wpin, dim3(512), dim3(256), 0, stream, pwin, wTin);
  hipLaunchKernelGGL(k_cvt_wpmid, dim3(3 * 512), dim3(256), 0, stream, pwmid, wTmid);
  hipLaunchKernelGGL(k_cvt_wpout, dim3(80), dim3(256), 0, stream, pwout, wTout);
  hipLaunchKernelGGL(k_p_ys, dim3(4000), dim3(96), 0, stream, ys, ysp);
  hipLaunchKernelGGL(k_p_w1, dim3(256), dim3(96), 0, stream, pW1, W1p);
  hipLaunchKernelGGL(k_p_w2, dim3(256), dim3(256), 0, stream, pW2, W2p);
  hipLaunchKernelGGL(k_p_wenc, dim3(128), dim3(256), 0, stream, W_enc, Wencp);
  hipLaunchKernelGGL(k_p_fw, dim3(128), dim3(256), 0, stream, featW, probW, featWp);

  // preenc: hs_h @ Wencp -> pe_h (transposed, +b_enc)
  hipLaunchKernelGGL((k_gemw<16, 1>), dim3(200, 2), dim3(256), 0, stream,
                     hs_h, Wencp, pe_h, nullptr, nullptr, b_enc);
  // prenet
  hipLaunchKernelGGL((k_gemw<3, 0>), dim3(250, 4), dim3(256), 0, stream,
                     ysp, W1p, h1p, nullptr, nullptr, nullptr);
  hipLaunchKernelGGL((k_gemw<8, 0>), dim3(250, 4), dim3(256), 0, stream,
                     h1p, W2p, pren_h, nullptr, nullptr, nullptr);

  // persistent scan (2 sync hops/step: z0w -> att -> aw; dp in att-block registers)
  ScanP S{pe_h, Mb, Wdr, hs_h, pren_h, W0ah, Whh0h, Wz01h, Whh1h,
          h0h, z1h, attc_h, gvw, b0, b1, hlens, z1all, flags};
  hipLaunchKernelGGL(k_scan, dim3(256), dim3(256), 0, stream, S);

  // heads
  hipLaunchKernelGGL((k_gemw<32, 2>), dim3(250, 2), dim3(256), 0, stream,
                     z1all, featWp, xT1, out1, out2, probB);

  // postnet
  hipLaunchKernelGGL((k_cvmf<128, 5, true, false>), dim3(16, 32), dim3(256), 0, stream,
                     xT1, wTin, pgin, pbin, xTA, nullptr, nullptr);
  hipLaunchKernelGGL((k_cvmf<512, 20, true, false>), dim3(16, 32), dim3(256), 0, stream,
                     xTA, wTmid, pgmid, pbmid, xTB, nullptr, nullptr);
  hipLaunchKernelGGL((k_cvmf<512, 20, true, false>), dim3(16, 32), dim3(256), 0, stream,
                     xTB, wTmid + (size_t)512 * 2560, pgmid + 512, pbmid + 512,
                     xTA, nullptr, nullptr);
  hipLaunchKernelGGL((k_cvmf<512, 20, true, false>), dim3(16, 32), dim3(256), 0, stream,
                     xTA, wTmid + (size_t)2 * 512 * 2560, pgmid + 1024, pbmid + 1024,
                     xTB, nullptr, nullptr);
  hipLaunchKernelGGL((k_cvmf<512, 20, false, true>), dim3(16, 5), dim3(256), 0, stream,
                     xTB, wTout, pgout, pbout, nullptr, out1, out0);
}

// Round 20
// 5784.525 us; speedup vs baseline: 1.2905x; 1.2905x over previous
//
#include <hip/hip_runtime.h>
#include <cstdint>
#include <cstddef>

// Problem constants
constexpr int B_ = 16, T_ = 200, L_ = 250;
constexpr int IDIM = 512, ODIM = 80, DUNITS = 1024;
constexpr int ADIM = 128, ACH = 32, AK = 31;
constexpr int PRE = 256;
constexpr int TPAD = 208;

typedef _Float16 h16;
typedef _Float16 half8 __attribute__((ext_vector_type(8)));
typedef _Float16 half4 __attribute__((ext_vector_type(4)));
typedef float f32x4 __attribute__((ext_vector_type(4)));

// store-only flags per step (ints): z0w[256] @0 ; dpw[32] @256 ; aw[16 reps][32] @288
constexpr int FSTEP = 800;
constexpr int FZ0W = 0, FDPW = 256, FAW = 288;

// ---- workspace byte offsets (16B-aligned) ----
constexpr size_t OFF_PE    = 0;          // pe_h   [16][128][208] f16
constexpr size_t OFF_H0H   = 851968;     // h0h    [2][16][1024] f16
constexpr size_t OFF_Z1H   = 917504;     // z1h    [2][16][1024] f16
constexpr size_t OFF_ATTC  = 983040;     // attc   [16][512] f16
constexpr size_t OFF_DP    = 999424;     // dp     [16][128] f32
constexpr size_t OFF_FLAGS = 1007616;    // flags  [250][800] int -> 1,807,616
constexpr size_t OFF_XT1   = 1807616;    // xT1 [16][264][128] f16 -> 2,888,960
constexpr size_t OFF_XTA   = 2888960;    // xTA [16][264][512] f16 -> 7,214,336
constexpr size_t OFF_XTB   = 7214336;    // xTB [16][264][512] f16 -> 11,539,712
constexpr size_t ZERO_BYTES= 11539712;   // zero span [0, here)
constexpr size_t OFF_MB    = 11539712;   // Mb     [8][64][8] f16
constexpr size_t OFF_WDR   = 11547904;   // Wdr    [128][1024] f16 (W_dec^T)
constexpr size_t OFF_PREN  = 11810048;   // pren_h [250][16][256] f16
constexpr size_t OFF_HSH   = 13858048;   // hs_h   [16][200][512] f16
constexpr size_t OFF_W0AH  = 17134848;   // W0ah   [4096][768]  f16
constexpr size_t OFF_WHH0  = 23426304;   // Whh0h  [4096][1024] f16
constexpr size_t OFF_WI1   = 31814912;   // Wz01h  [4096][1024] f16
constexpr size_t OFF_WHH1  = 40203520;   // Whh1h  [4096][1024] f16
constexpr size_t OFF_Z1ALL = 48592128;   // z1all  [250][16][1024] f16
constexpr size_t OFF_WTIN  = 56784128;   // wTin  [512][640]  f16
constexpr size_t OFF_WTMID = 57439488;   // wTmid [3][512][2560] f16
constexpr size_t OFF_WTOUT = 65303808;   // wTout [80][2560] f16 -> 65,713,408
constexpr size_t OFF_YSP   = 65713408;   // ysp [4000][96] f16 -> 66,481,408
constexpr size_t OFF_H1P   = 66481408;   // h1p [4000][256] f16 -> 68,529,408
constexpr size_t OFF_W1P   = 68529408;   // W1p [256][96] f16 -> 68,578,560
constexpr size_t OFF_W2P   = 68578560;   // W2p [256][256] f16 -> 68,709,632
constexpr size_t OFF_WENCP = 68709632;   // Wencp [128][512] f16 -> 68,840,704
constexpr size_t OFF_FWP   = 68840704;   // featWp [128][1024] f16 -> 69,102,848

__device__ __forceinline__ float fsig(float x) {
  x = fminf(fmaxf(x, -30.f), 30.f);
  return __builtin_amdgcn_rcpf(1.f + __expf(-x));
}
__device__ __forceinline__ float ftanh(float x) {
  x = fminf(fmaxf(x, -15.f), 15.f);
  const float e = __expf(2.f * x);
  return (e - 1.f) * __builtin_amdgcn_rcpf(e + 1.f);
}
__device__ __forceinline__ f32x4 mfma16(half8 a, half8 b, f32x4 c) {
  return __builtin_amdgcn_mfma_f32_16x16x32_f16(a, b, c, 0, 0, 0);
}
// agent-scope relaxed 16B load as 2x8B atomics (verified r8-r18 discipline)
__device__ __forceinline__ half8 load8_agent(const h16* p) {
  union { unsigned long long q[2]; half8 v; } cv;
  cv.q[0] = __hip_atomic_load((const unsigned long long*)p, __ATOMIC_RELAXED,
                              __HIP_MEMORY_SCOPE_AGENT);
  cv.q[1] = __hip_atomic_load(((const unsigned long long*)p) + 1, __ATOMIC_RELAXED,
                              __HIP_MEMORY_SCOPE_AGENT);
  return cv.v;
}
__device__ __forceinline__ float loadf_agent(const float* p) {
  union { unsigned u; float f; } cv;
  cv.u = __hip_atomic_load((const unsigned*)p, __ATOMIC_RELAXED,
                           __HIP_MEMORY_SCOPE_AGENT);
  return cv.f;
}
__device__ __forceinline__ void storef_agent(float* p, float v) {
  union { unsigned u; float f; } cv; cv.f = v;
  __hip_atomic_store((unsigned*)p, cv.u, __ATOMIC_RELAXED, __HIP_MEMORY_SCOPE_AGENT);
}
__device__ __forceinline__ int loadw(const int* p) {
  return __hip_atomic_load(p, __ATOMIC_RELAXED, __HIP_MEMORY_SCOPE_AGENT);
}
__device__ __forceinline__ void storew(int* p, int v) {
  __hip_atomic_store(p, v, __ATOMIC_RELAXED, __HIP_MEMORY_SCOPE_AGENT);
}
__device__ __forceinline__ void poll_n(const int* base, const int n) {
  if ((int)threadIdx.x < n) {
    const int* f = base + threadIdx.x;
    while (loadw(f) == 0) __builtin_amdgcn_s_sleep(1);
  }
  __syncthreads();
  __builtin_amdgcn_sched_barrier(0);
}
__device__ __forceinline__ void poll_all256(const int* base) {
  const int* f = base + threadIdx.x;
  while (loadw(f) == 0) __builtin_amdgcn_s_sleep(1);
  __syncthreads();
  __builtin_amdgcn_sched_barrier(0);
}

// ---------------- prep kernels ----------------

__global__ void k_zero(float4* __restrict__ p, int n4) {
  const int i = blockIdx.x * blockDim.x + threadIdx.x;
  if (i < n4) p[i] = make_float4(0.f, 0.f, 0.f, 0.f);
}

__global__ void k_precMb(const float* __restrict__ lconv, const float* __restrict__ W_att,
                         h16* __restrict__ Mb) {
  const int at = blockIdx.x, lane = threadIdx.x;
  const int a = at * 16 + (lane & 15);
  const int k0 = (lane >> 4) * 8;
  half8 o;
#pragma unroll
  for (int j = 0; j < 8; ++j) {
    const int k = k0 + j;
    float v = 0.f;
    if (k < AK)
      for (int c = 0; c < ACH; ++c) v += lconv[c * AK + k] * W_att[c * ADIM + a];
    o[j] = (h16)v;
  }
  *(half8*)(Mb + (size_t)(at * 64 + lane) * 8) = o;
}

__global__ void k_cvt_perm(const float* __restrict__ src, h16* __restrict__ dst,
                           const int K) {
  const int rr = blockIdx.x;
  const int u = rr >> 2, g = rr & 3;
  const float* s = src + (size_t)(g * 1024 + u) * K;
  h16* d = dst + (size_t)rr * K;
  for (int k = threadIdx.x; k < K; k += 256) d[k] = (h16)s[k];
}

// Wdr[a][k] = W_dec[k][a], f16
__global__ void k_cvt_wdec(const float* __restrict__ Wdec, h16* __restrict__ Wdr) {
  const int a = blockIdx.x;
  for (int k = threadIdx.x; k < 1024; k += 256)
    Wdr[(size_t)a * 1024 + k] = (h16)Wdec[(size_t)k * ADIM + a];
}

__global__ void k_cvt_f32f16(const float* __restrict__ src, h16* __restrict__ dst) {
  const size_t i = ((size_t)blockIdx.x * 256 + threadIdx.x) * 4;
  const float4 v = *(const float4*)(src + i);
  half4 o; o[0] = (h16)v.x; o[1] = (h16)v.y; o[2] = (h16)v.z; o[3] = (h16)v.w;
  *(half4*)(dst + i) = o;
}

// postnet weight repacks: wT[co][k*CIP + ci]
__global__ void k_cvt_wpin(const float* __restrict__ w, h16* __restrict__ o) {
  const int co = blockIdx.x;   // 512
  for (int i = threadIdx.x; i < 640; i += 256) {
    const int k = i >> 7, ci = i & 127;
    o[(size_t)co * 640 + i] = (ci < 80) ? (h16)w[((size_t)co * 80 + ci) * 5 + k] : (h16)0.f;
  }
}
__global__ void k_cvt_wpmid(const float* __restrict__ w, h16* __restrict__ o) {
  const int idx = blockIdx.x;  // 3*512
  const float* s = w + (size_t)idx * 512 * 5;
  h16* d = o + (size_t)idx * 2560;
  for (int i = threadIdx.x; i < 2560; i += 256) {
    const int k = i >> 9, ci = i & 511;
    d[i] = (h16)s[(size_t)ci * 5 + k];
  }
}
__global__ void k_cvt_wpout(const float* __restrict__ w, h16* __restrict__ o) {
  const int co = blockIdx.x;   // 80
  for (int i = threadIdx.x; i < 2560; i += 256) {
    const int k = i >> 9, ci = i & 511;
    o[(size_t)co * 2560 + i] = (h16)w[((size_t)co * 512 + ci) * 5 + k];
  }
}

// small GEMM prepacks
__global__ void k_p_ys(const float* __restrict__ ys, h16* __restrict__ ysp) {
  const int m = blockIdx.x;            // 4000: m = l*16+b
  const int l = m >> 4, b = m & 15;
  const int co = threadIdx.x;          // 96 threads
  h16 v = (h16)0.f;
  if (l > 0 && co < 80) v = (h16)ys[((size_t)b * L_ + (l - 1)) * ODIM + co];
  ysp[(size_t)m * 96 + co] = v;
}
__global__ void k_p_w1(const float* __restrict__ W1, h16* __restrict__ W1p) {
  const int p = blockIdx.x;            // 256
  const int o = threadIdx.x;           // 96
  W1p[(size_t)p * 96 + o] = (o < 80) ? (h16)W1[(size_t)o * PRE + p] : (h16)0.f;
}
__global__ void k_p_w2(const float* __restrict__ W2, h16* __restrict__ W2p) {
  const int p2 = blockIdx.x;           // 256
  const int p = threadIdx.x;           // 256
  W2p[(size_t)p2 * 256 + p] = (h16)W2[(size_t)p * PRE + p2];
}
__global__ void k_p_wenc(const float* __restrict__ We, h16* __restrict__ Wp) {
  const int a = blockIdx.x;            // 128
  for (int d = threadIdx.x; d < 512; d += 256)
    Wp[(size_t)a * 512 + d] = (h16)We[(size_t)d * ADIM + a];
}
__global__ void k_p_fw(const float* __restrict__ fw, const float* __restrict__ pw,
                       h16* __restrict__ Wp) {
  const int co = blockIdx.x;           // 128
  for (int d = threadIdx.x; d < 1024; d += 256) {
    h16 v = (h16)0.f;
    if (co < 80) v = (h16)fw[(size_t)d * ODIM + co];
    else if (co == 80) v = (h16)pw[d];
    Wp[(size_t)co * 1024 + d] = v;
  }
}

// ---------------- generic 16x64 MFMA GEMM (r17-verified) ----------------
template <int KCH, int EPI>
__global__ void __launch_bounds__(256) k_gemw(const h16* __restrict__ A,
    const h16* __restrict__ W, h16* __restrict__ dsth, float* __restrict__ dstf,
    float* __restrict__ dstf2, const float* __restrict__ bvec) {
  constexpr int KA = KCH * 32;
  const int m0 = blockIdx.x * 16, n0 = blockIdx.y * 64;
  const int lane = threadIdx.x & 63, wave = threadIdx.x >> 6;
  const int nloc = lane & 15, kl8 = (lane >> 4) * 8;
  const h16* wr = W + (size_t)(n0 + wave * 16 + nloc) * KA + kl8;
  half8 w[KCH];
#pragma unroll
  for (int c = 0; c < KCH; ++c) w[c] = *(const half8*)(wr + c * 32);
  const h16* ar = A + (size_t)(m0 + nloc) * KA + kl8;
  f32x4 acc = {0.f, 0.f, 0.f, 0.f};
#pragma unroll
  for (int c = 0; c < KCH; ++c)
    acc = mfma16(*(const half8*)(ar + c * 32), w[c], acc);
  const int n = n0 + wave * 16 + (lane & 15);
#pragma unroll
  for (int r = 0; r < 4; ++r) {
    const int m = m0 + 4 * (lane >> 4) + r;
    const float v = acc[r];
    if (EPI == 0) {
      dsth[(size_t)m * 256 + n] = (h16)fmaxf(v, 0.f);
    } else if (EPI == 1) {
      const int b = m / 200, t = m % 200;
      dsth[((size_t)b * 128 + n) * TPAD + t] = (h16)(v + bvec[n]);
    } else {
      const int b = m & 15, l = m >> 4;
      if (n < 80) {
        dstf[((size_t)b * L_ + l) * ODIM + n] = v;
        dsth[((size_t)b * 264 + l + 2) * 128 + n] = (h16)v;
      } else if (n == 80) {
        dstf2[(size_t)b * L_ + l] = v + bvec[0];
      }
    }
  }
}

// ---------------- MFMA postnet conv (r18-verified: weights once, loop b) ----------------
template <int CIP, int NK, bool TANH, bool FINAL>
__global__ void __launch_bounds__(256) k_cvmf(const h16* __restrict__ xT,
    const h16* __restrict__ wT, const float* __restrict__ gamma,
    const float* __restrict__ beta, h16* __restrict__ yT,
    const float* __restrict__ res, float* __restrict__ out0) {
  __shared__ float s_red[4][64][5];
  __shared__ float s_g[16][20];
  constexpr int KTOT = NK * 128;
  const int l0 = blockIdx.x * 16, co0 = blockIdx.y * 16;
  const int tid = threadIdx.x, lane = tid & 63, wave = tid >> 6;
  const int nloc = lane & 15, kl8 = (lane >> 4) * 8;
  const h16* wr = wT + (size_t)(co0 + nloc) * KTOT + wave * (NK * 32) + kl8;
  half8 w[NK];
#pragma unroll
  for (int c = 0; c < NK; ++c) w[c] = *(const half8*)(wr + c * 32);
  for (int b = 0; b < B_; ++b) {
    f32x4 acc = {0.f, 0.f, 0.f, 0.f};
    const h16* xb = xT + (size_t)b * 264 * CIP;
#pragma unroll
    for (int c = 0; c < NK; ++c) {
      const int kg = wave * (NK * 32) + c * 32;
      const int k = kg / CIP, ci = kg & (CIP - 1);
      const half8 a = *(const half8*)(xb + (size_t)(l0 + nloc + k) * CIP + ci + kl8);
      acc = mfma16(a, w[c], acc);
    }
#pragma unroll
    for (int r = 0; r < 4; ++r) s_red[wave][lane][r] = acc[r];
    __syncthreads();
    {
      const float v = s_red[0][lane][wave] + s_red[1][lane][wave]
                    + s_red[2][lane][wave] + s_red[3][lane][wave];
      s_g[lane & 15][4 * (lane >> 4) + wave] = v;
    }
    __syncthreads();
    {
      const int co_l = tid & 15, l_l = tid >> 4;
      const int co = co0 + co_l, l = l0 + l_l;
      if (l < L_ && tid < 256) {
        float v = gamma[co] * s_g[co_l][l_l] + beta[co];
        if (TANH) v = ftanh(v);
        if (FINAL) {
          const size_t o = ((size_t)b * L_ + l) * ODIM + co;
          out0[o] = res[o] + v;
        } else {
          yT[((size_t)b * 264 + l + 2) * 512 + co] = (h16)v;
        }
      }
    }
    __syncthreads();
  }
}

// ---------------- persistent scan (r14/r16/r17/r18 verbatim) ----------------

struct ScanP {
  const h16 *pe_h, *Mb, *Wdr, *hs_h, *pren_h;
  const h16 *W0ah, *Whh0h, *Wz01h, *Whh1h;
  h16 *h0h, *z1h, *attc;
  float *dp;
  const float *gvw, *b0, *b1;
  const int *hlens;
  h16 *z1all;
  int *flags;
};

__device__ __forceinline__ void lstm0_partA(const h16* pren_t, const h16* z0p,
    const half8 wA[6], const half8 wH[8], f32x4& acc) {
  const int lane = threadIdx.x & 63, wave = threadIdx.x >> 6;
  const int nloc = lane & 15, kl8 = (lane >> 4) * 8;
  half8 rz[8];
#pragma unroll
  for (int c = 0; c < 8; ++c)
    rz[c] = load8_agent(z0p + nloc * DUNITS + wave * 256 + c * 32 + kl8);
#pragma unroll
  for (int c = 0; c < 8; ++c) acc = mfma16(rz[c], wH[c], acc);
#pragma unroll
  for (int c = 0; c < 6; ++c) {
    const int kg = wave * 192 + c * 32;
    if (kg >= 512)
      acc = mfma16(*(const half8*)(pren_t + nloc * PRE + (kg - 512) + kl8), wA[c], acc);
  }
}

__device__ __forceinline__ void lstm0_partB(const ScanP& P,
    h16* z0o, const int slab, const half8 wA[6], float& c0reg, f32x4 acc,
    float sred[4][64][5], float sg[16][20], h16* sho) {
  const int tid = threadIdx.x;
  const int lane = tid & 63, wave = tid >> 6;
  const int nloc = lane & 15, kl8 = (lane >> 4) * 8;
  half8 ra[6];
#pragma unroll
  for (int c = 0; c < 6; ++c) {
    const int kg = wave * 192 + c * 32;
    if (kg < 512) ra[c] = load8_agent(P.attc + nloc * IDIM + kg + kl8);
  }
#pragma unroll
  for (int c = 0; c < 6; ++c) {
    const int kg = wave * 192 + c * 32;
    if (kg < 512) acc = mfma16(ra[c], wA[c], acc);
  }
#pragma unroll
  for (int r = 0; r < 4; ++r) sred[wave][lane][r] = acc[r];
  __syncthreads();
  {
    const float v = sred[0][lane][wave] + sred[1][lane][wave]
                  + sred[2][lane][wave] + sred[3][lane][wave];
    sg[lane & 15][4 * (lane >> 4) + wave] = v;
  }
  __syncthreads();
  if (tid < 64) {
    const int ul = tid >> 4, b = tid & 15;
    const int u = slab * 4 + ul;
    const float xi = sg[ul * 4 + 0][b] + P.b0[u];
    const float xf = sg[ul * 4 + 1][b] + P.b0[1024 + u];
    const float xg = sg[ul * 4 + 2][b] + P.b0[2048 + u];
    const float xo = sg[ul * 4 + 3][b] + P.b0[3072 + u];
    const float cn = fsig(xf) * c0reg + fsig(xi) * ftanh(xg);
    c0reg = cn;
    sho[ul * 16 + b] = (h16)(fsig(xo) * ftanh(cn));
  }
  __syncthreads();
  if (tid < 16) {
    union { h16 h[4]; unsigned long long q; } u4;
#pragma unroll
    for (int j = 0; j < 4; ++j) u4.h[j] = sho[j * 16 + tid];
    __hip_atomic_store((unsigned long long*)(z0o + tid * DUNITS + slab * 4), u4.q,
                       __ATOMIC_RELAXED, __HIP_MEMORY_SCOPE_AGENT);
  }
}

__device__ __forceinline__ void lstm1_mm(const ScanP& P, const half8 r0[8],
    const half8 r1[8], h16* z1o, h16* z1all_s, const int slab,
    const half8 wI[8], const half8 wHH[8], float& c1reg,
    float sred[4][64][5], float sg[16][20], h16* sho) {
  const int tid = threadIdx.x;
  const int lane = tid & 63, wave = tid >> 6;
  f32x4 acc = {0.f, 0.f, 0.f, 0.f};
#pragma unroll
  for (int c = 0; c < 8; ++c) acc = mfma16(r0[c], wI[c], acc);
#pragma unroll
  for (int c = 0; c < 8; ++c) acc = mfma16(r1[c], wHH[c], acc);
#pragma unroll
  for (int r = 0; r < 4; ++r) sred[wave][lane][r] = acc[r];
  __syncthreads();
  {
    const float v = sred[0][lane][wave] + sred[1][lane][wave]
                  + sred[2][lane][wave] + sred[3][lane][wave];
    sg[lane & 15][4 * (lane >> 4) + wave] = v;
  }
  __syncthreads();
  if (tid < 64) {
    const int ul = tid >> 4, b = tid & 15;
    const int u = slab * 4 + ul;
    const float xi = sg[ul * 4 + 0][b] + P.b1[u];
    const float xf = sg[ul * 4 + 1][b] + P.b1[1024 + u];
    const float xg = sg[ul * 4 + 2][b] + P.b1[2048 + u];
    const float xo = sg[ul * 4 + 3][b] + P.b1[3072 + u];
    const float cn = fsig(xf) * c1reg + fsig(xi) * ftanh(xg);
    c1reg = cn;
    const float hn = fsig(xo) * ftanh(cn);
    const h16 hh = (h16)hn;
    z1all_s[b * DUNITS + u] = hh;
    sho[ul * 16 + b] = hh;
  }
  __syncthreads();
  if (tid < 16) {
    union { h16 h[4]; unsigned long long q; } u4;
#pragma unroll
    for (int j = 0; j < 4; ++j) u4.h[j] = sho[j * 16 + tid];
    __hip_atomic_store((unsigned long long*)(z1o + tid * DUNITS + slab * 4), u4.q,
                       __ATOMIC_RELAXED, __HIP_MEMORY_SCOPE_AGENT);
  }
}

__global__ void __launch_bounds__(256, 1) k_scan(const ScanP P) {
  __shared__ float s_red[4][64][5];
  __shared__ float s_g[16][20];
  __shared__ h16   s_ho[64];
  __shared__ float s_aw[240];
  __shared__ float s_dp[ADIM];
  __shared__ float s_gv[ADIM];
  __shared__ float s_ew[256];
  __shared__ float s_wt[208];
  __shared__ float s_par[4][512];
  __shared__ float s_r8[8];
  __shared__ float s_bc[2];
  __shared__ float s_cvpe[13][8][64][4];

  const int blk = blockIdx.x, tid = threadIdx.x;
  const int lane = tid & 63, wave = tid >> 6;
  constexpr int BD = B_ * DUNITS;

  if (blk < 16) {
    const int b = blk;
    const int hl = P.hlens[b];
    const int mtmax = (hl + 15) >> 4;
    const int slab = 240 + b;
    const int l15 = lane & 15;
    half8 bfrag[8];
#pragma unroll
    for (int at = 0; at < 8; ++at)
      bfrag[at] = *(const half8*)(P.Mb + (size_t)(at * 64 + lane) * 8);
    half8 wA[6], wH[8];
    {
      const int nloc = lane & 15, kl8 = (lane >> 4) * 8;
      const h16* wrA = P.W0ah + ((size_t)(slab * 16 + nloc)) * 768 + wave * 192 + kl8;
      const h16* wrH = P.Whh0h + ((size_t)(slab * 16 + nloc)) * 1024 + wave * 256 + kl8;
#pragma unroll
      for (int c = 0; c < 6; ++c) wA[c] = *(const half8*)(wrA + c * 32);
#pragma unroll
      for (int c = 0; c < 8; ++c) wH[c] = *(const half8*)(wrH + c * 32);
    }
    if (tid < 240) {
      const int tt = tid - 15;
      s_aw[tid] = (tt >= 0 && tt < hl) ? (1.f / (float)hl) : 0.f;
    }
    if (tid < ADIM) s_gv[tid] = P.gvw[tid];
    __syncthreads();
    float c0reg = 0.f;

    for (int mi = 0; mi < 4; ++mi) {
      const int mt = wave + mi * 4;
      if (mt < mtmax) {
        half8 af;
#pragma unroll
        for (int j = 0; j < 8; ++j)
          af[j] = (h16)s_aw[mt * 16 + l15 + (lane >> 4) * 8 + j];
        const int t0 = mt * 16 + 4 * (lane >> 4);
        half4 pe[8];
#pragma unroll
        for (int at = 0; at < 8; ++at)
          pe[at] = *(const half4*)(P.pe_h + ((size_t)b * ADIM + at * 16 + l15) * TPAD + t0);
#pragma unroll
        for (int at = 0; at < 8; ++at) {
          f32x4 z4 = {0.f, 0.f, 0.f, 0.f};
          const f32x4 cv = mfma16(af, bfrag[at], z4);
          float4 o;
          o.x = cv[0] + (float)pe[at][0]; o.y = cv[1] + (float)pe[at][1];
          o.z = cv[2] + (float)pe[at][2]; o.w = cv[3] + (float)pe[at][3];
          *(float4*)&s_cvpe[mt][at][lane][0] = o;
        }
      }
    }
    __syncthreads();

    for (int i = 0; i < L_; ++i) {
      const h16* z0p = P.h0h + (size_t)(i & 1) * BD;
      h16* z0o = P.h0h + (size_t)((i & 1) ^ 1) * BD;
      int* sf = P.flags + (size_t)i * FSTEP;
      poll_n(sf + FDPW, 8);
      if (tid < ADIM) s_dp[tid] = loadf_agent(P.dp + b * ADIM + tid);
      __syncthreads();
#pragma unroll
      for (int mi = 0; mi < 4; ++mi) {
        const int mt = wave + mi * 4;
        if (mt < mtmax) {
          const int t0 = mt * 16 + 4 * (lane >> 4);
          float e0 = 0.f, e1 = 0.f, e2 = 0.f, e3 = 0.f;
#pragma unroll
          for (int at = 0; at < 8; ++at) {
            const float4 v = *(const float4*)&s_cvpe[mt][at][lane][0];
            const int a = at * 16 + l15;
            const float g = s_gv[a], d = s_dp[a];
            e0 += g * ftanh(v.x + d);
            e1 += g * ftanh(v.y + d);
            e2 += g * ftanh(v.z + d);
            e3 += g * ftanh(v.w + d);
          }
#pragma unroll
          for (int o = 1; o < 16; o <<= 1) {
            e0 += __shfl_xor(e0, o); e1 += __shfl_xor(e1, o);
            e2 += __shfl_xor(e2, o); e3 += __shfl_xor(e3, o);
          }
          if (l15 == 0) {
            s_ew[t0 + 0] = e0; s_ew[t0 + 1] = e1; s_ew[t0 + 2] = e2; s_ew[t0 + 3] = e3;
          }
        }
      }
      __syncthreads();
      const float val = (tid < hl) ? 2.f * s_ew[tid] : -3.0e38f;
      float m = val;
#pragma unroll
      for (int o = 32; o > 0; o >>= 1) m = fmaxf(m, __shfl_xor(m, o));
      if ((tid & 63) == 0) s_r8[tid >> 6] = m;
      __syncthreads();
      if (tid == 0) s_bc[0] = fmaxf(fmaxf(s_r8[0], s_r8[1]), fmaxf(s_r8[2], s_r8[3]));
      __syncthreads();
      const float pp = (tid < hl) ? __expf(val - s_bc[0]) : 0.f;
      float ssum = pp;
#pragma unroll
      for (int o = 32; o > 0; o >>= 1) ssum += __shfl_xor(ssum, o);
      if ((tid & 63) == 0) s_r8[4 + (tid >> 6)] = ssum;
      __syncthreads();
      if (tid == 0) s_bc[1] = __builtin_amdgcn_rcpf(s_r8[4] + s_r8[5] + s_r8[6] + s_r8[7]);
      __syncthreads();
      if (tid < T_) {
        const float w = pp * s_bc[1];
        s_wt[tid] = w;
        s_aw[15 + tid] = w;
      }
      __syncthreads();
      const h16* hsb = P.hs_h + (size_t)b * T_ * IDIM;
      {
        const int d0 = lane * 8;
        const h16* hp = hsb + d0;
        float a8[8] = {0.f, 0.f, 0.f, 0.f, 0.f, 0.f, 0.f, 0.f};
        int tt = wave;
        for (; tt + 12 < hl; tt += 16) {
          const half8 h0 = *(const half8*)(hp + (size_t)tt * IDIM);
          const half8 h1 = *(const half8*)(hp + (size_t)(tt + 4) * IDIM);
          const half8 h2 = *(const half8*)(hp + (size_t)(tt + 8) * IDIM);
          const half8 h3 = *(const half8*)(hp + (size_t)(tt + 12) * IDIM);
          const float w0 = s_wt[tt], w1 = s_wt[tt + 4];
          const float w2 = s_wt[tt + 8], w3 = s_wt[tt + 12];
#pragma unroll
          for (int j = 0; j < 8; ++j)
            a8[j] += w0 * (float)h0[j] + w1 * (float)h1[j]
                   + w2 * (float)h2[j] + w3 * (float)h3[j];
        }
        for (; tt < hl; tt += 4) {
          const half8 hv = *(const half8*)(hp + (size_t)tt * IDIM);
          const float wt = s_wt[tt];
#pragma unroll
          for (int j = 0; j < 8; ++j) a8[j] += wt * (float)hv[j];
        }
#pragma unroll
        for (int j = 0; j < 8; ++j) s_par[wave][d0 + j] = a8[j];
      }
      __syncthreads();
      {
        const int d = tid * 2;
        const float cx0 = s_par[0][d] + s_par[1][d] + s_par[2][d] + s_par[3][d];
        const float cx1 = s_par[0][d + 1] + s_par[1][d + 1] + s_par[2][d + 1]
                        + s_par[3][d + 1];
        union { h16 h[2]; unsigned u; } cv;
        cv.h[0] = (h16)cx0; cv.h[1] = (h16)cx1;
        __hip_atomic_store((unsigned*)(P.attc + b * IDIM + d), cv.u,
                           __ATOMIC_RELAXED, __HIP_MEMORY_SCOPE_AGENT);
      }
      asm volatile("s_waitcnt vmcnt(0)" ::: "memory");
      __syncthreads();
      if (tid < 16) storew(sf + FAW + tid * 32 + b, 1);
      f32x4 acc0 = {0.f, 0.f, 0.f, 0.f};
      lstm0_partA(P.pren_h + (size_t)i * (B_ * PRE), z0p, wA, wH, acc0);
      poll_n(sf + FAW + (blk & 15) * 32, 16);
      lstm0_partB(P, z0o, slab, wA, c0reg, acc0, s_red, s_g, s_ho);
      asm volatile("s_waitcnt vmcnt(0)" ::: "memory");
      __syncthreads();
      if (tid == 0) storew(sf + FZ0W + blk, 1);
      for (int mi = 0; mi < 4; ++mi) {
        const int mt = wave + mi * 4;
        if (mt < mtmax) {
          half8 af;
#pragma unroll
          for (int j = 0; j < 8; ++j)
            af[j] = (h16)s_aw[mt * 16 + l15 + (lane >> 4) * 8 + j];
          const int t0 = mt * 16 + 4 * (lane >> 4);
          half4 pe[8];
#pragma unroll
          for (int at = 0; at < 8; ++at)
            pe[at] = *(const half4*)(P.pe_h + ((size_t)b * ADIM + at * 16 + l15) * TPAD + t0);
#pragma unroll
          for (int at = 0; at < 8; ++at) {
            f32x4 z4 = {0.f, 0.f, 0.f, 0.f};
            const f32x4 cv = mfma16(af, bfrag[at], z4);
            float4 o;
            o.x = cv[0] + (float)pe[at][0]; o.y = cv[1] + (float)pe[at][1];
            o.z = cv[2] + (float)pe[at][2]; o.w = cv[3] + (float)pe[at][3];
            *(float4*)&s_cvpe[mt][at][lane][0] = o;
          }
        }
      }
      __syncthreads();
    }
    return;
  }

  // ============ GEMM block ============
  const int g = blk - 16;
  const bool dbl = (g < 16);
  const bool isdp = (g >= 16 && g < 24);
  half8 wA0[6], wH0[8], wI1a[8], wHH1a[8], wI1b[8], wHH1b[8], wD[8];
  {
    const int nloc = lane & 15, kl8 = (lane >> 4) * 8;
    const h16* wrA = P.W0ah + ((size_t)(g * 16 + nloc)) * 768 + wave * 192 + kl8;
    const h16* wrH = P.Whh0h + ((size_t)(g * 16 + nloc)) * 1024 + wave * 256 + kl8;
    const h16* wrI = P.Wz01h + ((size_t)(g * 16 + nloc)) * 1024 + wave * 256 + kl8;
    const h16* wrX = P.Whh1h + ((size_t)(g * 16 + nloc)) * 1024 + wave * 256 + kl8;
#pragma unroll
    for (int c = 0; c < 6; ++c) wA0[c] = *(const half8*)(wrA + c * 32);
#pragma unroll
    for (int c = 0; c < 8; ++c) wH0[c] = *(const half8*)(wrH + c * 32);
#pragma unroll
    for (int c = 0; c < 8; ++c) wI1a[c] = *(const half8*)(wrI + c * 32);
#pragma unroll
    for (int c = 0; c < 8; ++c) wHH1a[c] = *(const half8*)(wrX + c * 32);
    if (dbl) {
      const h16* wrI2 = P.Wz01h + ((size_t)((240 + g) * 16 + nloc)) * 1024 + wave * 256 + kl8;
      const h16* wrX2 = P.Whh1h + ((size_t)((240 + g) * 16 + nloc)) * 1024 + wave * 256 + kl8;
#pragma unroll
      for (int c = 0; c < 8; ++c) wI1b[c] = *(const half8*)(wrI2 + c * 32);
#pragma unroll
      for (int c = 0; c < 8; ++c) wHH1b[c] = *(const half8*)(wrX2 + c * 32);
    }
    if (isdp) {
      const h16* wrD = P.Wdr + ((size_t)((g - 16) * 16 + nloc)) * 1024 + wave * 256 + kl8;
#pragma unroll
      for (int c = 0; c < 8; ++c) wD[c] = *(const half8*)(wrD + c * 32);
    }
  }
  float c0reg = 0.f, c1a = 0.f, c1b = 0.f;
  const int nloc = lane & 15, kl8 = (lane >> 4) * 8;

  for (int i = 0; i < L_; ++i) {
    const h16* z0p = P.h0h + (size_t)(i & 1) * BD;
    h16* z0o = P.h0h + (size_t)((i & 1) ^ 1) * BD;
    const h16* z1p = P.z1h + (size_t)((i & 1) ^ 1) * BD;
    h16* z1o = P.z1h + (size_t)(i & 1) * BD;
    int* sf = P.flags + (size_t)i * FSTEP;
    if (i > 0) poll_all256(P.flags + (size_t)(i - 1) * FSTEP + FZ0W);
    if (isdp) {
      half8 rz[8];
#pragma unroll
      for (int c = 0; c < 8; ++c)
        rz[c] = load8_agent(z0p + nloc * DUNITS + wave * 256 + c * 32 + kl8);
      f32x4 acc = {0.f, 0.f, 0.f, 0.f};
#pragma unroll
      for (int c = 0; c < 8; ++c) acc = mfma16(rz[c], wD[c], acc);
#pragma unroll
      for (int r = 0; r < 4; ++r) s_red[wave][lane][r] = acc[r];
      __syncthreads();
      {
        const float v = s_red[0][lane][wave] + s_red[1][lane][wave]
                      + s_red[2][lane][wave] + s_red[3][lane][wave];
        const int row = lane & 15, batch = 4 * (lane >> 4) + wave;
        storef_agent(P.dp + batch * ADIM + (g - 16) * 16 + row, v);
      }
      asm volatile("s_waitcnt vmcnt(0)" ::: "memory");
      __syncthreads();
      if (tid == 0) storew(sf + FDPW + (g - 16), 1);
    }
    if (i > 0) {
      half8 r0[8], r1[8];
#pragma unroll
      for (int c = 0; c < 8; ++c)
        r0[c] = load8_agent(z0p + nloc * DUNITS + wave * 256 + c * 32 + kl8);
#pragma unroll
      for (int c = 0; c < 8; ++c)
        r1[c] = load8_agent(z1p + nloc * DUNITS + wave * 256 + c * 32 + kl8);
      h16* z1s = P.z1all + (size_t)(i - 1) * BD;
      lstm1_mm(P, r0, r1, z1o, z1s, g, wI1a, wHH1a, c1a, s_red, s_g, s_ho);
      if (dbl)
        lstm1_mm(P, r0, r1, z1o, z1s, 240 + g, wI1b, wHH1b, c1b, s_red, s_g, s_ho);
    }
    f32x4 acc0 = {0.f, 0.f, 0.f, 0.f};
    lstm0_partA(P.pren_h + (size_t)i * (B_ * PRE), z0p, wA0, wH0, acc0);
    poll_n(sf + FAW + (blk & 15) * 32, 16);
    lstm0_partB(P, z0o, g, wA0, c0reg, acc0, s_red, s_g, s_ho);
    asm volatile("s_waitcnt vmcnt(0)" ::: "memory");
    __syncthreads();
    if (tid == 0) storew(sf + FZ0W + blk, 1);
  }
  poll_all256(P.flags + (size_t)(L_ - 1) * FSTEP + FZ0W);
  {
    const h16* z0p = P.h0h + (size_t)(L_ & 1) * BD;
    const h16* z1p = P.z1h + (size_t)((L_ & 1) ^ 1) * BD;
    h16* z1o = P.z1h + (size_t)(L_ & 1) * BD;
    h16* z1s = P.z1all + (size_t)(L_ - 1) * BD;
    half8 r0[8], r1[8];
#pragma unroll
    for (int c = 0; c < 8; ++c)
      r0[c] = load8_agent(z0p + nloc * DUNITS + wave * 256 + c * 32 + kl8);
#pragma unroll
    for (int c = 0; c < 8; ++c)
      r1[c] = load8_agent(z1p + nloc * DUNITS + wave * 256 + c * 32 + kl8);
    lstm1_mm(P, r0, r1, z1o, z1s, g, wI1a, wHH1a, c1a, s_red, s_g, s_ho);
    if (dbl)
      lstm1_mm(P, r0, r1, z1o, z1s, 240 + g, wI1b, wHH1b, c1b, s_red, s_g, s_ho);
  }
}

// ---------------- launch ----------------

extern "C" void kernel_launch(void* const* d_in, const int* in_sizes, int n_in,
                              void* d_out, int out_size, void* d_ws, size_t ws_size,
                              hipStream_t stream) {
  const float* hs    = (const float*)d_in[0];
  const int*   hlens = (const int*)d_in[1];
  const float* ys    = (const float*)d_in[2];
  const float* W_enc = (const float*)d_in[3];
  const float* b_enc = (const float*)d_in[4];
  const float* W_dec = (const float*)d_in[5];
  const float* W_att = (const float*)d_in[6];
  const float* lconv = (const float*)d_in[7];
  const float* gvw   = (const float*)d_in[8];
  const float* pW1   = (const float*)d_in[10];
  const float* pW2   = (const float*)d_in[11];
  const float* Wih0  = (const float*)d_in[12];
  const float* Whh0  = (const float*)d_in[13];
  const float* b0    = (const float*)d_in[14];
  const float* Wih1  = (const float*)d_in[15];
  const float* Whh1  = (const float*)d_in[16];
  const float* b1    = (const float*)d_in[17];
  const float* featW = (const float*)d_in[18];
  const float* probW = (const float*)d_in[19];
  const float* probB = (const float*)d_in[20];
  const float* pwin  = (const float*)d_in[21];
  const float* pgin  = (const float*)d_in[22];
  const float* pbin  = (const float*)d_in[23];
  const float* pwmid = (const float*)d_in[24];
  const float* pgmid = (const float*)d_in[25];
  const float* pbmid = (const float*)d_in[26];
  const float* pwout = (const float*)d_in[27];
  const float* pgout = (const float*)d_in[28];
  const float* pbout = (const float*)d_in[29];

  char* ws = (char*)d_ws;
  h16*   pe_h   = (h16*)(ws + OFF_PE);
  h16*   h0h    = (h16*)(ws + OFF_H0H);
  h16*   z1h    = (h16*)(ws + OFF_Z1H);
  h16*   attc_h = (h16*)(ws + OFF_ATTC);
  float* dp     = (float*)(ws + OFF_DP);
  int*   flags  = (int*)(ws + OFF_FLAGS);
  h16*   xT1    = (h16*)(ws + OFF_XT1);
  h16*   xTA    = (h16*)(ws + OFF_XTA);
  h16*   xTB    = (h16*)(ws + OFF_XTB);
  h16*   Mb     = (h16*)(ws + OFF_MB);
  h16*   Wdr    = (h16*)(ws + OFF_WDR);
  h16*   pren_h = (h16*)(ws + OFF_PREN);
  h16*   hs_h   = (h16*)(ws + OFF_HSH);
  h16*   W0ah   = (h16*)(ws + OFF_W0AH);
  h16*   Whh0h  = (h16*)(ws + OFF_WHH0);
  h16*   Wz01h  = (h16*)(ws + OFF_WI1);
  h16*   Whh1h  = (h16*)(ws + OFF_WHH1);
  h16*   z1all  = (h16*)(ws + OFF_Z1ALL);
  h16*   wTin   = (h16*)(ws + OFF_WTIN);
  h16*   wTmid  = (h16*)(ws + OFF_WTMID);
  h16*   wTout  = (h16*)(ws + OFF_WTOUT);
  h16*   ysp    = (h16*)(ws + OFF_YSP);
  h16*   h1p    = (h16*)(ws + OFF_H1P);
  h16*   W1p    = (h16*)(ws + OFF_W1P);
  h16*   W2p    = (h16*)(ws + OFF_W2P);
  h16*   Wencp  = (h16*)(ws + OFF_WENCP);
  h16*   featWp = (h16*)(ws + OFF_FWP);

  float* out0 = (float*)d_out;
  float* out1 = out0 + (size_t)B_ * L_ * ODIM;
  float* out2 = out1 + (size_t)B_ * L_ * ODIM;

  // prep
  hipLaunchKernelGGL(k_zero, dim3((ZERO_BYTES / 16 + 255) / 256), dim3(256), 0, stream,
                     (float4*)ws, (int)(ZERO_BYTES / 16));
  hipLaunchKernelGGL(k_precMb, dim3(8), dim3(64), 0, stream, lconv, W_att, Mb);
  hipLaunchKernelGGL(k_cvt_perm, dim3(4096), dim3(256), 0, stream, Wih0, W0ah, 768);
  hipLaunchKernelGGL(k_cvt_perm, dim3(4096), dim3(256), 0, stream, Whh0, Whh0h, 1024);
  hipLaunchKernelGGL(k_cvt_perm, dim3(4096), dim3(256), 0, stream, Wih1, Wz01h, 1024);
  hipLaunchKernelGGL(k_cvt_perm, dim3(4096), dim3(256), 0, stream, Whh1, Whh1h, 1024);
  hipLaunchKernelGGL(k_cvt_wdec, dim3(128), dim3(256), 0, stream, W_dec, Wdr);
  hipLaunchKernelGGL(k_cvt_f32f16, dim3(1600), dim3(256), 0, stream, hs, hs_h);
  hipLaunchKernelGGL(k_cvt_wpin, dim3(512), dim3(256), 0, stream, pwin, wTin);
  hipLaunchKernelGGL(k_cvt_wpmid, dim3(3 * 512), dim3(256), 0, stream, pwmid, wTmid);
  hipLaunchKernelGGL(k_cvt_wpout, dim3(80), dim3(256), 0, stream, pwout, wTout);
  hipLaunchKernelGGL(k_p_ys, dim3(4000), dim3(96), 0, stream, ys, ysp);
  hipLaunchKernelGGL(k_p_w1, dim3(256), dim3(96), 0, stream, pW1, W1p);
  hipLaunchKernelGGL(k_p_w2, dim3(256), dim3(256), 0, stream, pW2, W2p);
  hipLaunchKernelGGL(k_p_wenc, dim3(128), dim3(256), 0, stream, W_enc, Wencp);
  hipLaunchKernelGGL(k_p_fw, dim3(128), dim3(256), 0, stream, featW, probW, featWp);

  // preenc: hs_h @ Wencp -> pe_h (transposed, +b_enc)
  hipLaunchKernelGGL((k_gemw<16, 1>), dim3(200, 2), dim3(256), 0, stream,
                     hs_h, Wencp, pe_h, nullptr, nullptr, b_enc);
  // prenet
  hipLaunchKernelGGL((k_gemw<3, 0>), dim3(250, 4), dim3(256), 0, stream,
                     ysp, W1p, h1p, nullptr, nullptr, nullptr);
  hipLaunchKernelGGL((k_gemw<8, 0>), dim3(250, 4), dim3(256), 0, stream,
                     h1p, W2p, pren_h, nullptr, nullptr, nullptr);

  // persistent scan (r14/r16/r17/r18 structure, verbatim)
  ScanP S{pe_h, Mb, Wdr, hs_h, pren_h, W0ah, Whh0h, Wz01h, Whh1h,
          h0h, z1h, attc_h, dp, gvw, b0, b1, hlens, z1all, flags};
  hipLaunchKernelGGL(k_scan, dim3(256), dim3(256), 0, stream, S);

  // heads
  hipLaunchKernelGGL((k_gemw<32, 2>), dim3(250, 2), dim3(256), 0, stream,
                     z1all, featWp, xT1, out1, out2, probB);

  // postnet
  hipLaunchKernelGGL((k_cvmf<128, 5, true, false>), dim3(16, 32), dim3(256), 0, stream,
                     xT1, wTin, pgin, pbin, xTA, nullptr, nullptr);
  hipLaunchKernelGGL((k_cvmf<512, 20, true, false>), dim3(16, 32), dim3(256), 0, stream,
                     xTA, wTmid, pgmid, pbmid, xTB, nullptr, nullptr);
  hipLaunchKernelGGL((k_cvmf<512, 20, true, false>), dim3(16, 32), dim3(256), 0, stream,
                     xTB, wTmid + (size_t)512 * 2560, pgmid + 512, pbmid + 512,
                     xTA, nullptr, nullptr);
  hipLaunchKernelGGL((k_cvmf<512, 20, true, false>), dim3(16, 32), dim3(256), 0, stream,
                     xTA, wTmid + (size_t)2 * 512 * 2560, pgmid + 1024, pbmid + 1024,
                     xTB, nullptr, nullptr);
  hipLaunchKernelGGL((k_cvmf<512, 20, false, true>), dim3(16, 5), dim3(256), 0, stream,
                     xTB, wTout, pgout, pbout, nullptr, out1, out0);
}